// Round 1
// baseline (38.294 us; speedup 1.0000x reference)
//
#include <hip/hip_runtime.h>
#include <hip/hip_bf16.h>

#define BLK 1024
#define NWAVES (BLK / 64)
#define MAXS 512

// One block per batch. Sequential chunked scan (1024 points/chunk) with
// stable per-octant rank via wave ballots + cross-wave LDS prefix.
// Early-exits once all 8 octants have >= 512 samples (~21k of 200k points
// for N(0,1) data), so we read ~12% of the input.
__global__ __launch_bounds__(BLK) void octant_query_kernel(
    const float* __restrict__ pcs, int* __restrict__ out, int N) {
  const int b = blockIdx.x;
  const float* __restrict__ xp = pcs + (size_t)b * 3 * N;
  const float* __restrict__ yp = xp + N;
  const float* __restrict__ zp = yp + N;
  int* __restrict__ obase = out + (size_t)b * 8 * MAXS;

  __shared__ unsigned cnt[NWAVES][8];
  __shared__ unsigned base[8];

  const int tid = threadIdx.x;
  const int wid = tid >> 6;
  const int lane = tid & 63;
  const unsigned long long ltmask = (lane == 63) ? 0x7fffffffffffffffull
                                                 : ((1ull << lane) - 1ull);

  // Init this batch's output slice to -1 (overwritten for filled slots).
  for (int i = tid; i < 8 * MAXS; i += BLK) obase[i] = -1;
  if (tid < 8) base[tid] = 0;
  __syncthreads();

  const int nChunks = (N + BLK - 1) / BLK;

  // Depth-2 prefetch pipeline registers.
  float x0, y0, z0, x1, y1, z1;

  // Sentinel 2.0f => r2 >= 4 => never within radius (also covers i >= N).
  #define LOADCHUNK(K, X, Y, Z)                          \
    do {                                                 \
      int _i = (K) * BLK + tid;                          \
      bool _v = ((K) < nChunks) && (_i < N);             \
      X = _v ? xp[_i] : 2.0f;                            \
      Y = _v ? yp[_i] : 2.0f;                            \
      Z = _v ? zp[_i] : 2.0f;                            \
    } while (0)

  LOADCHUNK(0, x0, y0, z0);
  LOADCHUNK(1, x1, y1, z1);

  for (int k = 0; k < nChunks; ++k) {
    const float x = x0, y = y0, z = z0;
    x0 = x1; y0 = y1; z0 = z1;
    LOADCHUNK(k + 2, x1, y1, z1);

    // Exact per-op IEEE f32 rounding to match the numpy reference
    // (no FMA contraction: boundary points r2 ~= 1.0 are order-sensitive).
    const float r2 = __fadd_rn(__fadd_rn(__fmul_rn(x, x), __fmul_rn(y, y)),
                               __fmul_rn(z, z));
    const bool within = (r2 <= 1.0f);
    const int oct = ((x >= 0.0f) ? 4 : 0) | ((y >= 0.0f) ? 2 : 0) |
                    ((z >= 0.0f) ? 1 : 0);
    const bool member = within;  // sentinel handles i >= N

    // Per-octant wave membership masks (named regs; no runtime array idx).
    const unsigned long long m0 = __ballot(member && oct == 0);
    const unsigned long long m1 = __ballot(member && oct == 1);
    const unsigned long long m2 = __ballot(member && oct == 2);
    const unsigned long long m3 = __ballot(member && oct == 3);
    const unsigned long long m4 = __ballot(member && oct == 4);
    const unsigned long long m5 = __ballot(member && oct == 5);
    const unsigned long long m6 = __ballot(member && oct == 6);
    const unsigned long long m7 = __ballot(member && oct == 7);

    if (lane == 0) {
      cnt[wid][0] = (unsigned)__popcll(m0);
      cnt[wid][1] = (unsigned)__popcll(m1);
      cnt[wid][2] = (unsigned)__popcll(m2);
      cnt[wid][3] = (unsigned)__popcll(m3);
      cnt[wid][4] = (unsigned)__popcll(m4);
      cnt[wid][5] = (unsigned)__popcll(m5);
      cnt[wid][6] = (unsigned)__popcll(m6);
      cnt[wid][7] = (unsigned)__popcll(m7);
    }
    __syncthreads();  // cnt visible

    // Select own octant's mask without register array indexing.
    unsigned long long mym = m7;
    mym = (oct == 0) ? m0 : mym;
    mym = (oct == 1) ? m1 : mym;
    mym = (oct == 2) ? m2 : mym;
    mym = (oct == 3) ? m3 : mym;
    mym = (oct == 4) ? m4 : mym;
    mym = (oct == 5) ? m5 : mym;
    mym = (oct == 6) ? m6 : mym;

    unsigned rank = base[oct] + (unsigned)__popcll(mym & ltmask);
    #pragma unroll
    for (int w = 0; w < NWAVES; ++w) {
      // cnt[w][0..7]: 8 distinct banks; same-address lanes broadcast.
      unsigned c = cnt[w][oct];
      rank += (w < wid) ? c : 0u;
    }

    if (member && rank < MAXS) {
      obase[oct * MAXS + (int)rank] = k * BLK + tid;
    }
    __syncthreads();  // all reads of base/cnt done

    if (tid < 8) {
      unsigned t = 0;
      #pragma unroll
      for (int w = 0; w < NWAVES; ++w) t += cnt[w][tid];
      base[tid] += t;
    }
    __syncthreads();  // base updated; cnt free for rewrite

    // Uniform early exit: all octants full.
    if (base[0] >= MAXS && base[1] >= MAXS && base[2] >= MAXS &&
        base[3] >= MAXS && base[4] >= MAXS && base[5] >= MAXS &&
        base[6] >= MAXS && base[7] >= MAXS)
      break;
  }
  #undef LOADCHUNK
}

extern "C" void kernel_launch(void* const* d_in, const int* in_sizes, int n_in,
                              void* d_out, int out_size, void* d_ws, size_t ws_size,
                              hipStream_t stream) {
  const float* pcs = (const float*)d_in[0];
  int* out = (int*)d_out;
  const int B = out_size / (8 * MAXS);          // 16
  const int N = in_sizes[0] / (3 * B);          // 200000
  octant_query_kernel<<<B, BLK, 0, stream>>>(pcs, out, N);
}

// Round 2
// 29.114 us; speedup vs baseline: 1.3153x; 1.3153x over previous
//
#include <hip/hip_runtime.h>

#define MAXS 512
#define SEG 3200      // segment size: multiple of 1024 pts? no — multiple of 4 and 256; 63 segs for N=200000
#define SMAX 64       // max segments per batch supported by the 64-lane scan
#define CBLK 256

// ---------------- Phase 1: per-(batch,segment,octant) counts ----------------
__global__ __launch_bounds__(CBLK) void count_kernel(
    const float* __restrict__ pcs, unsigned* __restrict__ counts,
    int N, int S) {
  const int bs = blockIdx.x;
  const int b = bs / S, s = bs - b * S;
  const int s0 = s * SEG;
  const int npts = min(SEG, N - s0);
  const float* __restrict__ xp = pcs + (size_t)b * 3 * N + s0;
  const float* __restrict__ yp = xp + N;
  const float* __restrict__ zp = yp + N;
  const int tid = threadIdx.x;
  const int wid = tid >> 6;
  const int lane = tid & 63;
  const int nf4 = npts >> 2;  // npts is a multiple of 4 here (N%4==0, SEG%4==0)

  unsigned c0 = 0, c1 = 0, c2 = 0, c3 = 0, c4 = 0, c5 = 0, c6 = 0, c7 = 0;

  for (int c = tid; c < nf4; c += CBLK) {
    const float4 x4 = ((const float4*)xp)[c];
    const float4 y4 = ((const float4*)yp)[c];
    const float4 z4 = ((const float4*)zp)[c];
    #define DO_PT(X, Y, Z)                                                     \
    do {                                                                       \
      const float r2 = __fadd_rn(                                              \
          __fadd_rn(__fmul_rn(X, X), __fmul_rn(Y, Y)), __fmul_rn(Z, Z));       \
      const bool member = (r2 <= 1.0f);                                        \
      const int oct = ((X >= 0.0f) ? 4 : 0) | ((Y >= 0.0f) ? 2 : 0) |          \
                      ((Z >= 0.0f) ? 1 : 0);                                   \
      c0 += (unsigned)__popcll(__ballot(member && oct == 0));                  \
      c1 += (unsigned)__popcll(__ballot(member && oct == 1));                  \
      c2 += (unsigned)__popcll(__ballot(member && oct == 2));                  \
      c3 += (unsigned)__popcll(__ballot(member && oct == 3));                  \
      c4 += (unsigned)__popcll(__ballot(member && oct == 4));                  \
      c5 += (unsigned)__popcll(__ballot(member && oct == 5));                  \
      c6 += (unsigned)__popcll(__ballot(member && oct == 6));                  \
      c7 += (unsigned)__popcll(__ballot(member && oct == 7));                  \
    } while (0)
    DO_PT(x4.x, y4.x, z4.x);
    DO_PT(x4.y, y4.y, z4.y);
    DO_PT(x4.z, y4.z, z4.z);
    DO_PT(x4.w, y4.w, z4.w);
    #undef DO_PT
  }
  // NOTE: ballots under the strided loop are exec-masked; inactive lanes
  // contribute 0 bits — exactly "no point", so counts stay correct.

  __shared__ unsigned wcnt[CBLK / 64][8];
  if (lane == 0) {
    wcnt[wid][0] = c0; wcnt[wid][1] = c1; wcnt[wid][2] = c2; wcnt[wid][3] = c3;
    wcnt[wid][4] = c4; wcnt[wid][5] = c5; wcnt[wid][6] = c6; wcnt[wid][7] = c7;
  }
  __syncthreads();
  if (tid < 8) {
    const unsigned t = wcnt[0][tid] + wcnt[1][tid] + wcnt[2][tid] + wcnt[3][tid];
    counts[((size_t)b * 8 + tid) * SMAX + s] = t;
  }
}

// ------- Phase 2: exclusive prefix over segments per (batch,octant); -------
// ------- also initialize this batch's output slice to -1.            -------
__global__ __launch_bounds__(512) void scan_kernel(
    const unsigned* __restrict__ counts, unsigned* __restrict__ bases,
    int* __restrict__ out, int S) {
  const int b = blockIdx.x;
  const int tid = threadIdx.x;
  int* __restrict__ ob = out + (size_t)b * 8 * MAXS;
  for (int i = tid; i < 8 * MAXS; i += 512) ob[i] = -1;

  const int o = tid >> 6;
  const int lane = tid & 63;
  const unsigned c =
      (lane < S) ? counts[((size_t)b * 8 + o) * SMAX + lane] : 0u;
  unsigned v = c;
  #pragma unroll
  for (int d = 1; d < 64; d <<= 1) {
    const unsigned t = __shfl_up(v, d, 64);
    if (lane >= d) v += t;
  }
  if (lane < S) bases[((size_t)b * 8 + o) * SMAX + lane] = v - c;
}

// ------- Phase 3: re-scan only segments whose bases aren't all full; -------
// ------- stable rank via wave ballots + cross-wave LDS prefix.       -------
__global__ __launch_bounds__(CBLK) void write_kernel(
    const float* __restrict__ pcs, const unsigned* __restrict__ bases,
    int* __restrict__ out, int N, int S) {
  const int bs = blockIdx.x;
  const int b = bs / S, s = bs - b * S;

  __shared__ unsigned base[8];
  __shared__ unsigned cnt[CBLK / 64][8];

  const int tid = threadIdx.x;
  const int wid = tid >> 6;
  const int lane = tid & 63;

  if (tid < 8) base[tid] = bases[((size_t)b * 8 + tid) * SMAX + s];
  __syncthreads();

  if (base[0] >= MAXS && base[1] >= MAXS && base[2] >= MAXS &&
      base[3] >= MAXS && base[4] >= MAXS && base[5] >= MAXS &&
      base[6] >= MAXS && base[7] >= MAXS)
    return;  // uniform: segment contributes nothing

  const int s0 = s * SEG;
  const int npts = min(SEG, N - s0);
  const float* __restrict__ xp = pcs + (size_t)b * 3 * N + s0;
  const float* __restrict__ yp = xp + N;
  const float* __restrict__ zp = yp + N;
  int* __restrict__ ob = out + (size_t)b * 8 * MAXS;

  const unsigned long long ltmask = (lane == 63) ? 0x7fffffffffffffffull
                                                 : ((1ull << lane) - 1ull);
  const int nch = (npts + CBLK - 1) / CBLK;

  for (int k = 0; k < nch; ++k) {
    const int idx = k * CBLK + tid;
    const bool v = idx < npts;
    // Sentinel 2.0f => r2 >= 4 => never a member.
    const float x = v ? xp[idx] : 2.0f;
    const float y = v ? yp[idx] : 2.0f;
    const float z = v ? zp[idx] : 2.0f;

    const float r2 = __fadd_rn(__fadd_rn(__fmul_rn(x, x), __fmul_rn(y, y)),
                               __fmul_rn(z, z));
    const bool member = (r2 <= 1.0f);
    const int oct = ((x >= 0.0f) ? 4 : 0) | ((y >= 0.0f) ? 2 : 0) |
                    ((z >= 0.0f) ? 1 : 0);

    const unsigned long long m0 = __ballot(member && oct == 0);
    const unsigned long long m1 = __ballot(member && oct == 1);
    const unsigned long long m2 = __ballot(member && oct == 2);
    const unsigned long long m3 = __ballot(member && oct == 3);
    const unsigned long long m4 = __ballot(member && oct == 4);
    const unsigned long long m5 = __ballot(member && oct == 5);
    const unsigned long long m6 = __ballot(member && oct == 6);
    const unsigned long long m7 = __ballot(member && oct == 7);

    if (lane == 0) {
      cnt[wid][0] = (unsigned)__popcll(m0);
      cnt[wid][1] = (unsigned)__popcll(m1);
      cnt[wid][2] = (unsigned)__popcll(m2);
      cnt[wid][3] = (unsigned)__popcll(m3);
      cnt[wid][4] = (unsigned)__popcll(m4);
      cnt[wid][5] = (unsigned)__popcll(m5);
      cnt[wid][6] = (unsigned)__popcll(m6);
      cnt[wid][7] = (unsigned)__popcll(m7);
    }
    __syncthreads();

    unsigned long long mym = m7;
    mym = (oct == 0) ? m0 : mym;
    mym = (oct == 1) ? m1 : mym;
    mym = (oct == 2) ? m2 : mym;
    mym = (oct == 3) ? m3 : mym;
    mym = (oct == 4) ? m4 : mym;
    mym = (oct == 5) ? m5 : mym;
    mym = (oct == 6) ? m6 : mym;

    unsigned rank = base[oct] + (unsigned)__popcll(mym & ltmask);
    #pragma unroll
    for (int w = 0; w < CBLK / 64; ++w) {
      const unsigned c = cnt[w][oct];
      rank += (w < wid) ? c : 0u;
    }

    if (member && rank < MAXS) ob[oct * MAXS + (int)rank] = s0 + idx;
    __syncthreads();

    if (tid < 8)
      base[tid] += cnt[0][tid] + cnt[1][tid] + cnt[2][tid] + cnt[3][tid];
    __syncthreads();

    if (base[0] >= MAXS && base[1] >= MAXS && base[2] >= MAXS &&
        base[3] >= MAXS && base[4] >= MAXS && base[5] >= MAXS &&
        base[6] >= MAXS && base[7] >= MAXS)
      break;
  }
}

extern "C" void kernel_launch(void* const* d_in, const int* in_sizes, int n_in,
                              void* d_out, int out_size, void* d_ws, size_t ws_size,
                              hipStream_t stream) {
  const float* pcs = (const float*)d_in[0];
  int* out = (int*)d_out;
  const int B = out_size / (8 * MAXS);   // 16
  const int N = in_sizes[0] / (3 * B);   // 200000
  const int S = (N + SEG - 1) / SEG;     // 63 (<= SMAX)

  unsigned* counts = (unsigned*)d_ws;                    // B*8*SMAX u32
  unsigned* bases = counts + (size_t)B * 8 * SMAX;       // B*8*SMAX u32

  count_kernel<<<B * S, CBLK, 0, stream>>>(pcs, counts, N, S);
  scan_kernel<<<B, 512, 0, stream>>>(counts, bases, out, S);
  write_kernel<<<B * S, CBLK, 0, stream>>>(pcs, bases, out, N, S);
}